// Round 1
// baseline (1091.607 us; speedup 1.0000x reference)
//
#include <hip/hip_runtime.h>
#include <cstdint>

#define Ssz 4096
#define Dsz 2048
#define Hn  16
#define Gn  4
#define HDn 128

typedef __attribute__((ext_vector_type(8))) short short8;
typedef __attribute__((ext_vector_type(8))) unsigned short u16x8;
typedef __attribute__((ext_vector_type(4))) float f32x4;

typedef __attribute__((address_space(1))) void gbl_void;
typedef __attribute__((address_space(3))) void lds_void;

static __device__ __forceinline__ unsigned short f2bf(float f) {
  uint32_t u = __builtin_bit_cast(uint32_t, f);
  u += 0x7FFFu + ((u >> 16) & 1u);   // RNE (no NaNs in this workload)
  return (unsigned short)(u >> 16);
}

// global -> LDS direct copy, 16B per lane. LDS dest must be wave-uniform base;
// HW adds lane*16. Cast via uintptr_t: low 32 bits of a generic LDS pointer
// are the LDS offset, full 64 bits of a global pointer are the VA.
static __device__ __forceinline__ void gload_lds16(const void* g, void* l) {
  __builtin_amdgcn_global_load_lds((gbl_void*)(uintptr_t)g,
                                   (lds_void*)(uintptr_t)l, 16, 0, 0);
}

// ---------------- cast f32 -> bf16, 8 elems/thread ----------------
__global__ void k_cast_bf16(const float* __restrict__ src,
                            unsigned short* __restrict__ dst, int n) {
  int base = (blockIdx.x * blockDim.x + threadIdx.x) * 8;
  if (base >= n) return;
  float4 a = *reinterpret_cast<const float4*>(src + base);
  float4 b = *reinterpret_cast<const float4*>(src + base + 4);
  u16x8 o;
  o[0] = f2bf(a.x); o[1] = f2bf(a.y); o[2] = f2bf(a.z); o[3] = f2bf(a.w);
  o[4] = f2bf(b.x); o[5] = f2bf(b.y); o[6] = f2bf(b.z); o[7] = f2bf(b.w);
  *reinterpret_cast<u16x8*>(dst + base) = o;
}

// ---------------- transpose f32 (R x C) -> bf16 (C x R), 64x64 tiles ----------------
__global__ void k_transpose(const float* __restrict__ src, int srcStride,
                            unsigned short* __restrict__ dst, int dstStride,
                            int R, int C) {
  __shared__ unsigned short tile[64][65];
  const int r0 = blockIdx.y * 64, c0 = blockIdx.x * 64;
  const int t  = threadIdx.x;
  const int rr = t >> 2;           // 0..63
  const int cc = (t & 3) * 16;     // 0,16,32,48
  const float* sp = src + (size_t)(r0 + rr) * srcStride + c0 + cc;
#pragma unroll
  for (int j = 0; j < 16; j += 4) {
    float4 v = *reinterpret_cast<const float4*>(sp + j);
    tile[rr][cc + j + 0] = f2bf(v.x);
    tile[rr][cc + j + 1] = f2bf(v.y);
    tile[rr][cc + j + 2] = f2bf(v.z);
    tile[rr][cc + j + 3] = f2bf(v.w);
  }
  __syncthreads();
  unsigned short* dp = dst + (size_t)(c0 + rr) * dstStride + r0 + cc;
  u16x8 o0, o1;
#pragma unroll
  for (int j = 0; j < 8; j++) o0[j] = tile[cc + j][rr];
#pragma unroll
  for (int j = 0; j < 8; j++) o1[j] = tile[cc + 8 + j][rr];
  *reinterpret_cast<u16x8*>(dp)     = o0;
  *reinterpret_cast<u16x8*>(dp + 8) = o1;
}

// ---------------- RoPE on Q (cols 0..2047) and K (cols 2048..2559) of Cqkv ----------------
__global__ void k_rope(const float* __restrict__ Cqkv,
                       const float* __restrict__ cosp, const float* __restrict__ sinp,
                       unsigned short* __restrict__ Qb, unsigned short* __restrict__ Kb) {
  const int s = blockIdx.x;
  const float* row = Cqkv + (size_t)s * 3072;
  const float qscale = 0.08838834764831845f;  // 1/sqrt(128)
  for (int c = threadIdx.x; c < 2560; c += 256) {
    int d = c & 127;
    float v = row[c];
    int pc = (d < 64) ? c + 64 : c - 64;
    float pv = row[pc];
    float rot = (d < 64) ? -pv : pv;
    float o = v * cosp[s * 128 + d] + rot * sinp[s * 128 + d];
    if (c < 2048)
      Qb[(size_t)s * 2048 + c] = f2bf(o * qscale);
    else
      Kb[(size_t)s * 512 + (c - 2048)] = f2bf(o);
  }
}

// ---------------- bf16 GEMM: C(f32, M x N, ldc) = A(M x K) * BT(N x K)^T ----------------
// m97 structure: 128x128 tile, BK=32, 4 waves (2x2), 4x4 16x16x32 frags per wave.
__global__ __launch_bounds__(256) void k_gemm_bt(
    const unsigned short* __restrict__ A, const unsigned short* __restrict__ BT,
    float* __restrict__ C, int M, int N, int K, int ldc) {
  __shared__ __align__(16) unsigned short sA[128 * 32];
  __shared__ __align__(16) unsigned short sB[128 * 32];
  const int tid = threadIdx.x;
  const int lane = tid & 63, wid = tid >> 6;
  const int m0 = blockIdx.y * 128, n0 = blockIdx.x * 128;
  const int wm = (wid >> 1) * 64, wn = (wid & 1) * 64;
  const int l15 = lane & 15, lg = lane >> 4;
  const int srow = lane >> 2;         // row within 16-row staging chunk
  const int scol = (lane & 3) * 8;    // elem col within BK

  f32x4 acc[4][4] = {};

  for (int kt = 0; kt < K; kt += 32) {
#pragma unroll
    for (int c = 0; c < 2; c++) {
      const int row = c * 64 + wid * 16;
      gload_lds16(A  + (size_t)(m0 + row + srow) * K + kt + scol, sA + row * 32);
      gload_lds16(BT + (size_t)(n0 + row + srow) * K + kt + scol, sB + row * 32);
    }
    __syncthreads();
    short8 af[4], bf[4];
#pragma unroll
    for (int i = 0; i < 4; i++) {
      af[i] = *reinterpret_cast<const short8*>(sA + (wm + i * 16 + l15) * 32 + lg * 8);
      bf[i] = *reinterpret_cast<const short8*>(sB + (wn + i * 16 + l15) * 32 + lg * 8);
    }
#pragma unroll
    for (int i = 0; i < 4; i++)
#pragma unroll
      for (int j = 0; j < 4; j++)
        acc[i][j] = __builtin_amdgcn_mfma_f32_16x16x32_bf16(af[i], bf[j], acc[i][j], 0, 0, 0);
    __syncthreads();
  }

  const int rbase = m0 + wm + lg * 4;
  const int cbase = n0 + wn + l15;
#pragma unroll
  for (int i = 0; i < 4; i++)
#pragma unroll
    for (int j = 0; j < 4; j++)
#pragma unroll
      for (int r = 0; r < 4; r++)
        C[(size_t)(rbase + i * 16 + r) * ldc + cbase + j * 16] = acc[i][j][r];
}

// ---------------- causal GQA flash attention ----------------
// Block: (q-tile of 64, head). 4 waves, each wave owns 16 q-rows -> no barriers.
// Q frags hoisted; K/Vt frags read from global (L2-resident); online softmax
// with 16-lane shfl reductions; P transposed through padded per-wave LDS.
__global__ __launch_bounds__(256) void k_attn(
    const unsigned short* __restrict__ Qb, const unsigned short* __restrict__ Kb,
    const unsigned short* __restrict__ Vt, unsigned short* __restrict__ ctx) {
  __shared__ __align__(16) unsigned short pl[4][16 * 72];  // [wave][16 q][64 kv], pad->72
  const int h = blockIdx.y, g = h >> 2;
  const int lane = threadIdx.x & 63, wid = threadIdx.x >> 6;
  const int l15 = lane & 15, lg = lane >> 4;
  const int qw0 = blockIdx.x * 64 + wid * 16;

  short8 qf[4];
  {
    const unsigned short* qp = Qb + (size_t)(qw0 + l15) * Dsz + h * HDn + lg * 8;
#pragma unroll
    for (int kk = 0; kk < 4; kk++)
      qf[kk] = *reinterpret_cast<const short8*>(qp + kk * 32);
  }

  f32x4 o[8] = {};
  float mrow[4], lrow[4];
#pragma unroll
  for (int r = 0; r < 4; r++) { mrow[r] = -1e30f; lrow[r] = 0.f; }

  unsigned short* plw = &pl[wid][0];
  const int nt = qw0 / 64 + 1;

  for (int t = 0; t < nt; t++) {
    const int kv0 = t * 64;
    f32x4 sc[4] = {};
#pragma unroll
    for (int f = 0; f < 4; f++) {
      const unsigned short* kp = Kb + (size_t)(kv0 + f * 16 + l15) * 512 + g * HDn + lg * 8;
#pragma unroll
      for (int kk = 0; kk < 4; kk++) {
        short8 kf = *reinterpret_cast<const short8*>(kp + kk * 32);
        sc[f] = __builtin_amdgcn_mfma_f32_16x16x32_bf16(qf[kk], kf, sc[f], 0, 0, 0);
      }
    }
    if (kv0 + 63 > qw0) {  // diagonal tile for this wave: apply causal mask
#pragma unroll
      for (int f = 0; f < 4; f++) {
        const int kv = kv0 + f * 16 + l15;
#pragma unroll
        for (int r = 0; r < 4; r++)
          if (kv > qw0 + lg * 4 + r) sc[f][r] = -1e30f;
      }
    }
    float mx[4], rs[4], scale[4];
#pragma unroll
    for (int r = 0; r < 4; r++)
      mx[r] = fmaxf(fmaxf(sc[0][r], sc[1][r]), fmaxf(sc[2][r], sc[3][r]));
#pragma unroll
    for (int off = 1; off < 16; off <<= 1)
#pragma unroll
      for (int r = 0; r < 4; r++) mx[r] = fmaxf(mx[r], __shfl_xor(mx[r], off));
#pragma unroll
    for (int r = 0; r < 4; r++) {
      float mn = fmaxf(mrow[r], mx[r]);
      scale[r] = __expf(mrow[r] - mn);
      mrow[r] = mn;
    }
#pragma unroll
    for (int f = 0; f < 4; f++)
#pragma unroll
      for (int r = 0; r < 4; r++) sc[f][r] = __expf(sc[f][r] - mrow[r]);
#pragma unroll
    for (int r = 0; r < 4; r++) rs[r] = sc[0][r] + sc[1][r] + sc[2][r] + sc[3][r];
#pragma unroll
    for (int off = 1; off < 16; off <<= 1)
#pragma unroll
      for (int r = 0; r < 4; r++) rs[r] += __shfl_xor(rs[r], off);
#pragma unroll
    for (int r = 0; r < 4; r++) lrow[r] = lrow[r] * scale[r] + rs[r];
#pragma unroll
    for (int nf = 0; nf < 8; nf++)
#pragma unroll
      for (int r = 0; r < 4; r++) o[nf][r] *= scale[r];

    // P (D-layout, row=4*lg+r, col=f*16+l15) -> LDS -> A-frag layout
#pragma unroll
    for (int f = 0; f < 4; f++)
#pragma unroll
      for (int r = 0; r < 4; r++)
        plw[(lg * 4 + r) * 72 + f * 16 + l15] = f2bf(sc[f][r]);

    short8 pa[2];
#pragma unroll
    for (int kk = 0; kk < 2; kk++)
      pa[kk] = *reinterpret_cast<const short8*>(plw + l15 * 72 + kk * 32 + lg * 8);

#pragma unroll
    for (int kk = 0; kk < 2; kk++) {
      const unsigned short* vp = Vt + (size_t)(g * HDn + l15) * Ssz + kv0 + kk * 32 + lg * 8;
#pragma unroll
      for (int nf = 0; nf < 8; nf++) {
        short8 vb = *reinterpret_cast<const short8*>(vp + (size_t)nf * 16 * Ssz);
        o[nf] = __builtin_amdgcn_mfma_f32_16x16x32_bf16(pa[kk], vb, o[nf], 0, 0, 0);
      }
    }
  }

  unsigned short* cp = ctx + (size_t)(qw0 + lg * 4) * Dsz + h * HDn + l15;
#pragma unroll
  for (int nf = 0; nf < 8; nf++)
#pragma unroll
    for (int r = 0; r < 4; r++)
      cp[(size_t)r * Dsz + nf * 16] = f2bf(o[nf][r] / lrow[r]);
}

extern "C" void kernel_launch(void* const* d_in, const int* in_sizes, int n_in,
                              void* d_out, int out_size, void* d_ws, size_t ws_size,
                              hipStream_t stream) {
  (void)in_sizes; (void)n_in; (void)out_size; (void)ws_size;
  const float* x  = (const float*)d_in[0];
  // d_in[1] = mask: causality is hardcoded, never read
  const float* wq = (const float*)d_in[2];
  const float* wk = (const float*)d_in[3];
  const float* wv = (const float*)d_in[4];
  const float* wo = (const float*)d_in[5];
  const float* cs = (const float*)d_in[6];
  const float* sn = (const float*)d_in[7];
  float* out = (float*)d_out;

  unsigned short* ws16  = (unsigned short*)d_ws;
  unsigned short* WTqkv = ws16;                          // 3072*2048 (wq^T|wk^T|wv^T)
  unsigned short* WTo   = WTqkv + 3072 * 2048;           // 2048*2048
  unsigned short* xb    = WTo   + 2048 * 2048;           // 4096*2048
  unsigned short* Qb    = xb    + 4096 * 2048;           // 4096*2048 (rope'd, *1/sqrt(HD))
  unsigned short* Kb    = Qb    + 4096 * 2048;           // 4096*512  (rope'd)
  unsigned short* Vt    = Kb    + 4096 * 512;            // 512*4096  (V transposed)
  unsigned short* ctx   = Vt    + 512 * 4096;            // 4096*2048
  float* Cqkv = (float*)(ctx + 4096 * 2048);             // 4096*3072 f32

  k_cast_bf16<<<4096, 256, 0, stream>>>(x, xb, 4096 * 2048);
  k_transpose<<<dim3(32, 32), 256, 0, stream>>>(wq, 2048, WTqkv,              2048, 2048, 2048);
  k_transpose<<<dim3(8, 32),  256, 0, stream>>>(wk, 512,  WTqkv + 2048 * 2048, 2048, 2048, 512);
  k_transpose<<<dim3(8, 32),  256, 0, stream>>>(wv, 512,  WTqkv + 2560 * 2048, 2048, 2048, 512);
  k_transpose<<<dim3(32, 32), 256, 0, stream>>>(wo, 2048, WTo,                2048, 2048, 2048);

  // Cqkv = xb @ [wq|wk|wv]
  k_gemm_bt<<<dim3(24, 32), 256, 0, stream>>>(xb, WTqkv, Cqkv, 4096, 3072, 2048, 3072);
  k_rope<<<4096, 256, 0, stream>>>(Cqkv, cs, sn, Qb, Kb);
  // Vt = (Cqkv V-block)^T, cast bf16
  k_transpose<<<dim3(8, 64), 256, 0, stream>>>(Cqkv + 2560, 3072, Vt, 4096, 4096, 512);

  k_attn<<<dim3(64, 16), 256, 0, stream>>>(Qb, Kb, Vt, ctx);

  // out = ctx @ wo
  k_gemm_bt<<<dim3(16, 32), 256, 0, stream>>>(ctx, WTo, out, 4096, 2048, 2048, 2048);
}

// Round 4
// 593.994 us; speedup vs baseline: 1.8377x; 1.8377x over previous
//
#include <hip/hip_runtime.h>
#include <cstdint>

#define Ssz 4096
#define Dsz 2048
#define Hn  16
#define Gn  4
#define HDn 128

typedef __attribute__((ext_vector_type(8))) short short8;
typedef __attribute__((ext_vector_type(8))) unsigned short u16x8;
typedef __attribute__((ext_vector_type(4))) float f32x4;

typedef __attribute__((address_space(1))) void gbl_void;
typedef __attribute__((address_space(3))) void lds_void;

static __device__ __forceinline__ unsigned short f2bf(float f) {
  uint32_t u = __builtin_bit_cast(uint32_t, f);
  u += 0x7FFFu + ((u >> 16) & 1u);   // RNE (no NaNs in this workload)
  return (unsigned short)(u >> 16);
}

// global -> LDS direct copy, 16B per lane. LDS dest is wave-uniform base
// (HW adds lane*16); global source address is per-lane.
static __device__ __forceinline__ void gload_lds16(const void* g, void* l) {
  __builtin_amdgcn_global_load_lds((gbl_void*)(uintptr_t)g,
                                   (lds_void*)(uintptr_t)l, 16, 0, 0);
}

// ---------------- cast f32 -> bf16, 8 elems/thread ----------------
__global__ void k_cast_bf16(const float* __restrict__ src,
                            unsigned short* __restrict__ dst, int n) {
  int base = (blockIdx.x * blockDim.x + threadIdx.x) * 8;
  if (base >= n) return;
  float4 a = *reinterpret_cast<const float4*>(src + base);
  float4 b = *reinterpret_cast<const float4*>(src + base + 4);
  u16x8 o;
  o[0] = f2bf(a.x); o[1] = f2bf(a.y); o[2] = f2bf(a.z); o[3] = f2bf(a.w);
  o[4] = f2bf(b.x); o[5] = f2bf(b.y); o[6] = f2bf(b.z); o[7] = f2bf(b.w);
  *reinterpret_cast<u16x8*>(dst + base) = o;
}

// ---------------- transpose f32 (R x C) -> bf16 (C x R), 64x64 tiles ----------------
__global__ void k_transpose(const float* __restrict__ src, int srcStride,
                            unsigned short* __restrict__ dst, int dstStride,
                            int R, int C) {
  __shared__ unsigned short tile[64][65];
  const int r0 = blockIdx.y * 64, c0 = blockIdx.x * 64;
  const int t  = threadIdx.x;
  const int rr = t >> 2;           // 0..63
  const int cc = (t & 3) * 16;     // 0,16,32,48
  const float* sp = src + (size_t)(r0 + rr) * srcStride + c0 + cc;
#pragma unroll
  for (int j = 0; j < 16; j += 4) {
    float4 v = *reinterpret_cast<const float4*>(sp + j);
    tile[rr][cc + j + 0] = f2bf(v.x);
    tile[rr][cc + j + 1] = f2bf(v.y);
    tile[rr][cc + j + 2] = f2bf(v.z);
    tile[rr][cc + j + 3] = f2bf(v.w);
  }
  __syncthreads();
  unsigned short* dp = dst + (size_t)(c0 + rr) * dstStride + r0 + cc;
  u16x8 o0, o1;
#pragma unroll
  for (int j = 0; j < 8; j++) o0[j] = tile[cc + j][rr];
#pragma unroll
  for (int j = 0; j < 8; j++) o1[j] = tile[cc + 8 + j][rr];
  *reinterpret_cast<u16x8*>(dp)     = o0;
  *reinterpret_cast<u16x8*>(dp + 8) = o1;
}

// ---------------- RoPE on Q (cols 0..2047) and K (cols 2048..2559) of Cqkv ----------------
__global__ void k_rope(const float* __restrict__ Cqkv,
                       const float* __restrict__ cosp, const float* __restrict__ sinp,
                       unsigned short* __restrict__ Qb, unsigned short* __restrict__ Kb) {
  const int s = blockIdx.x;
  const float* row = Cqkv + (size_t)s * 3072;
  const float qscale = 0.08838834764831845f;  // 1/sqrt(128)
  for (int c = threadIdx.x; c < 2560; c += 256) {
    int d = c & 127;
    float v = row[c];
    int pc = (d < 64) ? c + 64 : c - 64;
    float pv = row[pc];
    float rot = (d < 64) ? -pv : pv;
    float o = v * cosp[s * 128 + d] + rot * sinp[s * 128 + d];
    if (c < 2048)
      Qb[(size_t)s * 2048 + c] = f2bf(o * qscale);
    else
      Kb[(size_t)s * 512 + (c - 2048)] = f2bf(o);
  }
}

// ---------------- bf16 GEMM: C(f32, M x N, ldc) = A(M x K) * BT(N x K)^T ----------------
// m97 structure: 128x128 tile, BK=32, 4 waves (2x2), 4x4 16x16x32 frags per wave.
__global__ __launch_bounds__(256) void k_gemm_bt(
    const unsigned short* __restrict__ A, const unsigned short* __restrict__ BT,
    float* __restrict__ C, int M, int N, int K, int ldc) {
  __shared__ __align__(16) unsigned short sA[128 * 32];
  __shared__ __align__(16) unsigned short sB[128 * 32];
  const int tid = threadIdx.x;
  const int lane = tid & 63, wid = tid >> 6;
  const int m0 = blockIdx.y * 128, n0 = blockIdx.x * 128;
  const int wm = (wid >> 1) * 64, wn = (wid & 1) * 64;
  const int l15 = lane & 15, lg = lane >> 4;
  const int srow = lane >> 2;         // row within 16-row staging chunk
  const int scol = (lane & 3) * 8;    // elem col within BK

  f32x4 acc[4][4] = {};

  for (int kt = 0; kt < K; kt += 32) {
#pragma unroll
    for (int c = 0; c < 2; c++) {
      const int row = c * 64 + wid * 16;
      gload_lds16(A  + (size_t)(m0 + row + srow) * K + kt + scol, sA + row * 32);
      gload_lds16(BT + (size_t)(n0 + row + srow) * K + kt + scol, sB + row * 32);
    }
    __syncthreads();
    short8 af[4], bf[4];
#pragma unroll
    for (int i = 0; i < 4; i++) {
      af[i] = *reinterpret_cast<const short8*>(sA + (wm + i * 16 + l15) * 32 + lg * 8);
      bf[i] = *reinterpret_cast<const short8*>(sB + (wn + i * 16 + l15) * 32 + lg * 8);
    }
#pragma unroll
    for (int i = 0; i < 4; i++)
#pragma unroll
      for (int j = 0; j < 4; j++)
        acc[i][j] = __builtin_amdgcn_mfma_f32_16x16x32_bf16(af[i], bf[j], acc[i][j], 0, 0, 0);
    __syncthreads();
  }

  const int rbase = m0 + wm + lg * 4;
  const int cbase = n0 + wn + l15;
#pragma unroll
  for (int i = 0; i < 4; i++)
#pragma unroll
    for (int j = 0; j < 4; j++)
#pragma unroll
      for (int r = 0; r < 4; r++)
        C[(size_t)(rbase + i * 16 + r) * ldc + cbase + j * 16] = acc[i][j][r];
}

// ---------------- causal GQA flash attention, v2 ----------------
// Block: 128 q-rows x 1 head, 4 waves x 32 q-rows (2 M-frags each).
// K (64x128) and Vt (128x64) tiles double-buffered in LDS via global_load_lds,
// XOR-swizzled ((row&7)<<4) to kill the D=128 row-major bank conflict.
// Minimum 2-phase pipeline: barrier (drains prefetch) -> issue prefetch t+1
// -> compute t. P transposed q<->kv through XOR-swizzled per-wave LDS scratch.
__global__ __launch_bounds__(256, 2) void k_attn(
    const unsigned short* __restrict__ Qb, const unsigned short* __restrict__ Kb,
    const unsigned short* __restrict__ Vt, unsigned short* __restrict__ ctx) {
  __shared__ __align__(16) char sK[2][16384];   // [buf][64 kv][256B], swizzled
  __shared__ __align__(16) char sV[2][16384];   // [buf][128 d][128B], swizzled
  __shared__ __align__(16) char sP[4][4096];    // [wave][32 q][128B], swizzled
  const int h = blockIdx.y, g = h >> 2;
  const int lane = threadIdx.x & 63, wid = threadIdx.x >> 6;
  const int l15 = lane & 15, lg = lane >> 4;
  const int sw = (l15 & 7) << 4;
  const int qb = (int)(gridDim.x - 1 - blockIdx.x) * 128;  // longest blocks first
  const int wmin = qb + wid * 32;
  const int nt = qb / 64 + 2;

  // per-lane pre-swizzled staging source offsets (bytes)
  const char* kbyte = (const char*)Kb;
  const char* vbyte = (const char*)Vt;
  int kOff[4], vOff[4];
#pragma unroll
  for (int q = 0; q < 4; q++) {
    int rk = wid * 16 + q * 4 + (lane >> 4);            // K tile row 0..63
    kOff[q] = rk * 1024 + g * 256 + (((lane & 15) * 16) ^ ((rk & 7) << 4));
    int rv = wid * 32 + q * 8 + (lane >> 3);            // V tile row (d) 0..127
    vOff[q] = (g * 128 + rv) * 8192 + (((lane & 7) * 16) ^ ((rv & 7) << 4));
  }

  auto stage = [&](int t, int b) {
    const char* ks = kbyte + (size_t)t * 65536;   // kv0*1024
    const char* vs = vbyte + (size_t)t * 128;     // kv0*2
#pragma unroll
    for (int q = 0; q < 4; q++)
      gload_lds16(ks + kOff[q], &sK[b][(wid * 4 + q) * 1024]);
#pragma unroll
    for (int q = 0; q < 4; q++)
      gload_lds16(vs + vOff[q], &sV[b][(wid * 4 + q) * 1024]);
  };

  // hoist Q fragments (L2-resident)
  short8 qf[2][4];
#pragma unroll
  for (int m = 0; m < 2; m++) {
    const unsigned short* qp = Qb + (size_t)(wmin + m * 16 + l15) * Dsz + h * HDn + lg * 8;
#pragma unroll
    for (int kk = 0; kk < 4; kk++)
      qf[m][kk] = *reinterpret_cast<const short8*>(qp + kk * 32);
  }

  f32x4 o[2][8] = {};
  float mrow[2][4], lrow[2][4];
#pragma unroll
  for (int m = 0; m < 2; m++)
#pragma unroll
    for (int r = 0; r < 4; r++) { mrow[m][r] = -1e30f; lrow[m][r] = 0.f; }

  stage(0, 0);
  int cur = 0;

  for (int t = 0; t < nt; t++) {
    asm volatile("s_waitcnt vmcnt(0)" ::: "memory");
    __syncthreads();                       // tile t staged & buf cur^1 free
    if (t + 1 < nt) stage(t + 1, cur ^ 1); // prefetch overlaps compute below
    const int kv0 = t * 64;
    if (kv0 <= wmin + 31) {
      // ---- QK^T ----
      f32x4 sc[2][4] = {};
#pragma unroll
      for (int f = 0; f < 4; f++) {
        const char* kr = &sK[cur][(f * 16 + l15) * 256];
#pragma unroll
        for (int kk = 0; kk < 4; kk++) {
          short8 kf = *reinterpret_cast<const short8*>(kr + ((kk * 64 + lg * 16) ^ sw));
          sc[0][f] = __builtin_amdgcn_mfma_f32_16x16x32_bf16(qf[0][kk], kf, sc[0][f], 0, 0, 0);
          sc[1][f] = __builtin_amdgcn_mfma_f32_16x16x32_bf16(qf[1][kk], kf, sc[1][f], 0, 0, 0);
        }
      }
      // ---- causal mask (diagonal tiles only) ----
      if (kv0 + 63 > wmin) {
#pragma unroll
        for (int m = 0; m < 2; m++)
#pragma unroll
          for (int f = 0; f < 4; f++) {
            int kv = kv0 + f * 16 + l15;
#pragma unroll
            for (int r = 0; r < 4; r++)
              if (kv > wmin + m * 16 + lg * 4 + r) sc[m][f][r] = -1e30f;
          }
      }
      // ---- online softmax (rows live on 16-lane groups) ----
#pragma unroll
      for (int m = 0; m < 2; m++) {
        float mx[4], rs[4], scale[4];
#pragma unroll
        for (int r = 0; r < 4; r++)
          mx[r] = fmaxf(fmaxf(sc[m][0][r], sc[m][1][r]), fmaxf(sc[m][2][r], sc[m][3][r]));
#pragma unroll
        for (int off = 1; off < 16; off <<= 1)
#pragma unroll
          for (int r = 0; r < 4; r++) mx[r] = fmaxf(mx[r], __shfl_xor(mx[r], off));
#pragma unroll
        for (int r = 0; r < 4; r++) {
          float mn = fmaxf(mrow[m][r], mx[r]);
          scale[r] = __expf(mrow[m][r] - mn);
          mrow[m][r] = mn;
        }
#pragma unroll
        for (int f = 0; f < 4; f++)
#pragma unroll
          for (int r = 0; r < 4; r++) sc[m][f][r] = __expf(sc[m][f][r] - mrow[m][r]);
#pragma unroll
        for (int r = 0; r < 4; r++)
          rs[r] = sc[m][0][r] + sc[m][1][r] + sc[m][2][r] + sc[m][3][r];
#pragma unroll
        for (int off = 1; off < 16; off <<= 1)
#pragma unroll
          for (int r = 0; r < 4; r++) rs[r] += __shfl_xor(rs[r], off);
#pragma unroll
        for (int r = 0; r < 4; r++) lrow[m][r] = lrow[m][r] * scale[r] + rs[r];
#pragma unroll
        for (int nf = 0; nf < 8; nf++)
#pragma unroll
          for (int r = 0; r < 4; r++) o[m][nf][r] *= scale[r];
      }
      // ---- P -> swizzled LDS (transpose q<->kv), then A-frags ----
      char* plw = &sP[wid][0];
#pragma unroll
      for (int m = 0; m < 2; m++)
#pragma unroll
        for (int f = 0; f < 4; f++)
#pragma unroll
          for (int r = 0; r < 4; r++) {
            int row = m * 16 + lg * 4 + r;
            *reinterpret_cast<unsigned short*>(
                plw + row * 128 + ((f * 32 + l15 * 2) ^ ((row & 7) << 4))) =
                f2bf(sc[m][f][r]);
          }
      short8 pa[2][2];
#pragma unroll
      for (int m = 0; m < 2; m++)
#pragma unroll
        for (int kk = 0; kk < 2; kk++)
          pa[m][kk] = *reinterpret_cast<const short8*>(
              plw + (m * 16 + l15) * 128 + ((kk * 64 + lg * 16) ^ sw));
      // ---- PV ----
#pragma unroll
      for (int nf = 0; nf < 8; nf++) {
        const char* vr = &sV[cur][(nf * 16 + l15) * 128];
#pragma unroll
        for (int kk = 0; kk < 2; kk++) {
          short8 vb = *reinterpret_cast<const short8*>(vr + ((kk * 64 + lg * 16) ^ sw));
          o[0][nf] = __builtin_amdgcn_mfma_f32_16x16x32_bf16(pa[0][kk], vb, o[0][nf], 0, 0, 0);
          o[1][nf] = __builtin_amdgcn_mfma_f32_16x16x32_bf16(pa[1][kk], vb, o[1][nf], 0, 0, 0);
        }
      }
    }
    cur ^= 1;
  }

#pragma unroll
  for (int m = 0; m < 2; m++) {
    unsigned short* cp = ctx + (size_t)(wmin + m * 16 + lg * 4) * Dsz + h * HDn + l15;
#pragma unroll
    for (int nf = 0; nf < 8; nf++)
#pragma unroll
      for (int r = 0; r < 4; r++)
        cp[(size_t)r * Dsz + nf * 16] = f2bf(o[m][nf][r] / lrow[m][r]);
  }
}

extern "C" void kernel_launch(void* const* d_in, const int* in_sizes, int n_in,
                              void* d_out, int out_size, void* d_ws, size_t ws_size,
                              hipStream_t stream) {
  (void)in_sizes; (void)n_in; (void)out_size; (void)ws_size;
  const float* x  = (const float*)d_in[0];
  // d_in[1] = mask: causality is hardcoded, never read
  const float* wq = (const float*)d_in[2];
  const float* wk = (const float*)d_in[3];
  const float* wv = (const float*)d_in[4];
  const float* wo = (const float*)d_in[5];
  const float* cs = (const float*)d_in[6];
  const float* sn = (const float*)d_in[7];
  float* out = (float*)d_out;

  unsigned short* ws16  = (unsigned short*)d_ws;
  unsigned short* WTqkv = ws16;                          // 3072*2048 (wq^T|wk^T|wv^T)
  unsigned short* WTo   = WTqkv + 3072 * 2048;           // 2048*2048
  unsigned short* xb    = WTo   + 2048 * 2048;           // 4096*2048
  unsigned short* Qb    = xb    + 4096 * 2048;           // 4096*2048 (rope'd, *1/sqrt(HD))
  unsigned short* Kb    = Qb    + 4096 * 2048;           // 4096*512  (rope'd)
  unsigned short* Vt    = Kb    + 4096 * 512;            // 512*4096  (V transposed)
  unsigned short* ctx   = Vt    + 512 * 4096;            // 4096*2048
  float* Cqkv = (float*)(ctx + 4096 * 2048);             // 4096*3072 f32

  k_cast_bf16<<<4096, 256, 0, stream>>>(x, xb, 4096 * 2048);
  k_transpose<<<dim3(32, 32), 256, 0, stream>>>(wq, 2048, WTqkv,              2048, 2048, 2048);
  k_transpose<<<dim3(8, 32),  256, 0, stream>>>(wk, 512,  WTqkv + 2048 * 2048, 2048, 2048, 512);
  k_transpose<<<dim3(8, 32),  256, 0, stream>>>(wv, 512,  WTqkv + 2560 * 2048, 2048, 2048, 512);
  k_transpose<<<dim3(32, 32), 256, 0, stream>>>(wo, 2048, WTo,                2048, 2048, 2048);

  // Cqkv = xb @ [wq|wk|wv]
  k_gemm_bt<<<dim3(24, 32), 256, 0, stream>>>(xb, WTqkv, Cqkv, 4096, 3072, 2048, 3072);
  k_rope<<<4096, 256, 0, stream>>>(Cqkv, cs, sn, Qb, Kb);
  // Vt = (Cqkv V-block)^T, cast bf16
  k_transpose<<<dim3(8, 64), 256, 0, stream>>>(Cqkv + 2560, 3072, Vt, 4096, 4096, 512);

  k_attn<<<dim3(32, 16), 256, 0, stream>>>(Qb, Kb, Vt, ctx);

  // out = ctx @ wo
  k_gemm_bt<<<dim3(16, 32), 256, 0, stream>>>(ctx, WTo, out, 4096, 2048, 2048, 2048);
}

// Round 6
// 476.880 us; speedup vs baseline: 2.2891x; 1.2456x over previous
//
#include <hip/hip_runtime.h>
#include <cstdint>

#define Ssz 4096
#define Dsz 2048
#define Hn  16
#define Gn  4
#define HDn 128

typedef __attribute__((ext_vector_type(8))) short short8;
typedef __attribute__((ext_vector_type(8))) unsigned short u16x8;
typedef __attribute__((ext_vector_type(4))) float f32x4;

typedef __attribute__((address_space(1))) void gbl_void;
typedef __attribute__((address_space(3))) void lds_void;

static __device__ __forceinline__ unsigned short f2bf(float f) {
  uint32_t u = __builtin_bit_cast(uint32_t, f);
  u += 0x7FFFu + ((u >> 16) & 1u);   // RNE (no NaNs in this workload)
  return (unsigned short)(u >> 16);
}

// global -> LDS direct copy, 16B per lane. LDS dest is wave-uniform base
// (HW adds lane*16); global source address is per-lane.
static __device__ __forceinline__ void gload_lds16(const void* g, void* l) {
  __builtin_amdgcn_global_load_lds((gbl_void*)(uintptr_t)g,
                                   (lds_void*)(uintptr_t)l, 16, 0, 0);
}

// ---------------- cast f32 -> bf16, 8 elems/thread ----------------
__global__ void k_cast_bf16(const float* __restrict__ src,
                            unsigned short* __restrict__ dst, int n) {
  int base = (blockIdx.x * blockDim.x + threadIdx.x) * 8;
  if (base >= n) return;
  float4 a = *reinterpret_cast<const float4*>(src + base);
  float4 b = *reinterpret_cast<const float4*>(src + base + 4);
  u16x8 o;
  o[0] = f2bf(a.x); o[1] = f2bf(a.y); o[2] = f2bf(a.z); o[3] = f2bf(a.w);
  o[4] = f2bf(b.x); o[5] = f2bf(b.y); o[6] = f2bf(b.z); o[7] = f2bf(b.w);
  *reinterpret_cast<u16x8*>(dst + base) = o;
}

// ---------------- transpose f32 (R x C) -> bf16 (C x R), 64x64 tiles ----------------
__global__ void k_transpose(const float* __restrict__ src, int srcStride,
                            unsigned short* __restrict__ dst, int dstStride,
                            int R, int C) {
  __shared__ unsigned short tile[64][65];
  const int r0 = blockIdx.y * 64, c0 = blockIdx.x * 64;
  const int t  = threadIdx.x;
  const int rr = t >> 2;           // 0..63
  const int cc = (t & 3) * 16;     // 0,16,32,48
  const float* sp = src + (size_t)(r0 + rr) * srcStride + c0 + cc;
#pragma unroll
  for (int j = 0; j < 16; j += 4) {
    float4 v = *reinterpret_cast<const float4*>(sp + j);
    tile[rr][cc + j + 0] = f2bf(v.x);
    tile[rr][cc + j + 1] = f2bf(v.y);
    tile[rr][cc + j + 2] = f2bf(v.z);
    tile[rr][cc + j + 3] = f2bf(v.w);
  }
  __syncthreads();
  unsigned short* dp = dst + (size_t)(c0 + rr) * dstStride + r0 + cc;
  u16x8 o0, o1;
#pragma unroll
  for (int j = 0; j < 8; j++) o0[j] = tile[cc + j][rr];
#pragma unroll
  for (int j = 0; j < 8; j++) o1[j] = tile[cc + 8 + j][rr];
  *reinterpret_cast<u16x8*>(dp)     = o0;
  *reinterpret_cast<u16x8*>(dp + 8) = o1;
}

// ---------------- RoPE on Q (cols 0..2047) and K (cols 2048..2559) of Cqkv ----------------
__global__ void k_rope(const float* __restrict__ Cqkv,
                       const float* __restrict__ cosp, const float* __restrict__ sinp,
                       unsigned short* __restrict__ Qb, unsigned short* __restrict__ Kb) {
  const int s = blockIdx.x;
  const float* row = Cqkv + (size_t)s * 3072;
  const float qscale = 0.08838834764831845f;  // 1/sqrt(128)
  for (int c = threadIdx.x; c < 2560; c += 256) {
    int d = c & 127;
    float v = row[c];
    int pc = (d < 64) ? c + 64 : c - 64;
    float pv = row[pc];
    float rot = (d < 64) ? -pv : pv;
    float o = v * cosp[s * 128 + d] + rot * sinp[s * 128 + d];
    if (c < 2048)
      Qb[(size_t)s * 2048 + c] = f2bf(o * qscale);
    else
      Kb[(size_t)s * 512 + (c - 2048)] = f2bf(o);
  }
}

// ---------------- bf16 GEMM: C(f32, M x N, ldc) = A(M x K) * BT(N x K)^T ----------------
// m97 structure: 128x128 tile, BK=32, 4 waves (2x2), 4x4 16x16x32 frags per wave.
__global__ __launch_bounds__(256) void k_gemm_bt(
    const unsigned short* __restrict__ A, const unsigned short* __restrict__ BT,
    float* __restrict__ C, int M, int N, int K, int ldc) {
  __shared__ __align__(16) unsigned short sA[128 * 32];
  __shared__ __align__(16) unsigned short sB[128 * 32];
  const int tid = threadIdx.x;
  const int lane = tid & 63, wid = tid >> 6;
  const int m0 = blockIdx.y * 128, n0 = blockIdx.x * 128;
  const int wm = (wid >> 1) * 64, wn = (wid & 1) * 64;
  const int l15 = lane & 15, lg = lane >> 4;
  const int srow = lane >> 2;         // row within 16-row staging chunk
  const int scol = (lane & 3) * 8;    // elem col within BK

  f32x4 acc[4][4] = {};

  for (int kt = 0; kt < K; kt += 32) {
#pragma unroll
    for (int c = 0; c < 2; c++) {
      const int row = c * 64 + wid * 16;
      gload_lds16(A  + (size_t)(m0 + row + srow) * K + kt + scol, sA + row * 32);
      gload_lds16(BT + (size_t)(n0 + row + srow) * K + kt + scol, sB + row * 32);
    }
    __syncthreads();
    short8 af[4], bf[4];
#pragma unroll
    for (int i = 0; i < 4; i++) {
      af[i] = *reinterpret_cast<const short8*>(sA + (wm + i * 16 + l15) * 32 + lg * 8);
      bf[i] = *reinterpret_cast<const short8*>(sB + (wn + i * 16 + l15) * 32 + lg * 8);
    }
#pragma unroll
    for (int i = 0; i < 4; i++)
#pragma unroll
      for (int j = 0; j < 4; j++)
        acc[i][j] = __builtin_amdgcn_mfma_f32_16x16x32_bf16(af[i], bf[j], acc[i][j], 0, 0, 0);
    __syncthreads();
  }

  const int rbase = m0 + wm + lg * 4;
  const int cbase = n0 + wn + l15;
#pragma unroll
  for (int i = 0; i < 4; i++)
#pragma unroll
    for (int j = 0; j < 4; j++)
#pragma unroll
      for (int r = 0; r < 4; r++)
        C[(size_t)(rbase + i * 16 + r) * ldc + cbase + j * 16] = acc[i][j][r];
}

// ---------------- causal GQA flash attention, v3 ----------------
// Block: 128 q-rows x 1 head, 8 waves x 16 q-rows (512 thr) -> 16 waves/CU.
// blockIdx remap: ids i and i+256 get complementary q-tiles (31-j, j); under
// round-robin dispatch they share a CU -> per-CU work ~constant (68 units).
// K (64x128) and Vt (128x64) double-buffered LDS via global_load_lds,
// XOR-swizzled; 2-phase pipeline; defer-rescale (THR=8).
__global__ __launch_bounds__(512, 4) void k_attn(
    const unsigned short* __restrict__ Qb, const unsigned short* __restrict__ Kb,
    const unsigned short* __restrict__ Vt, unsigned short* __restrict__ ctx) {
  __shared__ __align__(16) char sK[2][16384];   // [buf][64 kv][256B], swizzled
  __shared__ __align__(16) char sV[2][16384];   // [buf][128 d][128B], swizzled
  __shared__ __align__(16) char sP[8][2048];    // [wave][16 q][128B], swizzled
  const int id = blockIdx.x;                    // 0..511
  const int kid = id & 255;
  const int h = kid & 15, g = h >> 2;
  const int j = kid >> 4;                       // 0..15
  const int qt = (id < 256) ? (31 - j) : j;     // long blocks first
  const int qb = qt * 128;
  const int lane = threadIdx.x & 63, wid = threadIdx.x >> 6;
  const int l15 = lane & 15, lg = lane >> 4;
  const int sw = (l15 & 7) << 4;
  const int wmin = qb + wid * 16;
  const int nt = qt * 2 + 2;

  // per-lane pre-swizzled staging source offsets (bytes)
  const char* kbyte = (const char*)Kb;
  const char* vbyte = (const char*)Vt;
  int kOff[2], vOff[2];
#pragma unroll
  for (int q = 0; q < 2; q++) {
    int rk = wid * 8 + q * 4 + (lane >> 4);             // K tile row 0..63
    kOff[q] = rk * 1024 + g * 256 + (((lane & 15) * 16) ^ ((rk & 7) << 4));
    int rv = wid * 16 + q * 8 + (lane >> 3);            // V tile row (d) 0..127
    vOff[q] = (g * 128 + rv) * 8192 + (((lane & 7) * 16) ^ ((rv & 7) << 4));
  }

  auto stage = [&](int t, int b) {
    const char* ks = kbyte + (size_t)t * 65536;   // kv0*1024
    const char* vs = vbyte + (size_t)t * 128;     // kv0*2
#pragma unroll
    for (int q = 0; q < 2; q++)
      gload_lds16(ks + kOff[q], &sK[b][(wid * 2 + q) * 1024]);
#pragma unroll
    for (int q = 0; q < 2; q++)
      gload_lds16(vs + vOff[q], &sV[b][(wid * 2 + q) * 1024]);
  };

  // hoist Q fragments (L2-resident)
  short8 qf[4];
  {
    const unsigned short* qp = Qb + (size_t)(wmin + l15) * Dsz + h * HDn + lg * 8;
#pragma unroll
    for (int kk = 0; kk < 4; kk++)
      qf[kk] = *reinterpret_cast<const short8*>(qp + kk * 32);
  }

  f32x4 o[8] = {};
  float mrow[4], lrow[4];
#pragma unroll
  for (int r = 0; r < 4; r++) { mrow[r] = -1e30f; lrow[r] = 0.f; }

  stage(0, 0);
  int cur = 0;

  for (int t = 0; t < nt; t++) {
    asm volatile("s_waitcnt vmcnt(0)" ::: "memory");
    __syncthreads();                       // tile t staged & buf cur^1 free
    if (t + 1 < nt) stage(t + 1, cur ^ 1); // prefetch overlaps compute below
    const int kv0 = t * 64;
    if (kv0 <= wmin + 15) {
      // ---- QK^T ----
      f32x4 sc[4] = {};
#pragma unroll
      for (int f = 0; f < 4; f++) {
        const char* kr = &sK[cur][(f * 16 + l15) * 256];
#pragma unroll
        for (int kk = 0; kk < 4; kk++) {
          short8 kf = *reinterpret_cast<const short8*>(kr + ((kk * 64 + lg * 16) ^ sw));
          sc[f] = __builtin_amdgcn_mfma_f32_16x16x32_bf16(qf[kk], kf, sc[f], 0, 0, 0);
        }
      }
      // ---- causal mask (diagonal tiles only) ----
      if (kv0 + 63 > wmin) {
#pragma unroll
        for (int f = 0; f < 4; f++) {
          int kv = kv0 + f * 16 + l15;
#pragma unroll
          for (int r = 0; r < 4; r++)
            if (kv > wmin + lg * 4 + r) sc[f][r] = -1e30f;
        }
      }
      // ---- online softmax (rows live on 16-lane groups) ----
      float mx[4], rs[4];
#pragma unroll
      for (int r = 0; r < 4; r++)
        mx[r] = fmaxf(fmaxf(sc[0][r], sc[1][r]), fmaxf(sc[2][r], sc[3][r]));
#pragma unroll
      for (int off = 1; off < 16; off <<= 1)
#pragma unroll
        for (int r = 0; r < 4; r++) mx[r] = fmaxf(mx[r], __shfl_xor(mx[r], off));
      // defer-rescale: only rescale when max grew by > 8
      bool grow = false;
#pragma unroll
      for (int r = 0; r < 4; r++) grow = grow || (mx[r] > mrow[r] + 8.f);
      if (__any(grow)) {
#pragma unroll
        for (int r = 0; r < 4; r++) {
          float mn = fmaxf(mrow[r], mx[r]);
          float scale = __expf(mrow[r] - mn);
          mrow[r] = mn;
          lrow[r] *= scale;
#pragma unroll
          for (int nf = 0; nf < 8; nf++) o[nf][r] *= scale;
        }
      }
#pragma unroll
      for (int f = 0; f < 4; f++)
#pragma unroll
        for (int r = 0; r < 4; r++) sc[f][r] = __expf(sc[f][r] - mrow[r]);
#pragma unroll
      for (int r = 0; r < 4; r++)
        rs[r] = sc[0][r] + sc[1][r] + sc[2][r] + sc[3][r];
#pragma unroll
      for (int off = 1; off < 16; off <<= 1)
#pragma unroll
        for (int r = 0; r < 4; r++) rs[r] += __shfl_xor(rs[r], off);
#pragma unroll
      for (int r = 0; r < 4; r++) lrow[r] += rs[r];

      // ---- P -> swizzled LDS (transpose q<->kv), then A-frags ----
      char* plw = &sP[wid][0];
#pragma unroll
      for (int f = 0; f < 4; f++)
#pragma unroll
        for (int r = 0; r < 4; r++) {
          int row = lg * 4 + r;
          *reinterpret_cast<unsigned short*>(
              plw + row * 128 + ((f * 32 + l15 * 2) ^ ((row & 7) << 4))) =
              f2bf(sc[f][r]);
        }
      short8 pa[2];
#pragma unroll
      for (int kk = 0; kk < 2; kk++)
        pa[kk] = *reinterpret_cast<const short8*>(
            plw + l15 * 128 + ((kk * 64 + lg * 16) ^ sw));
      // ---- PV ----
#pragma unroll
      for (int nf = 0; nf < 8; nf++) {
        const char* vr = &sV[cur][(nf * 16 + l15) * 128];
#pragma unroll
        for (int kk = 0; kk < 2; kk++) {
          short8 vb = *reinterpret_cast<const short8*>(vr + ((kk * 64 + lg * 16) ^ sw));
          o[nf] = __builtin_amdgcn_mfma_f32_16x16x32_bf16(pa[kk], vb, o[nf], 0, 0, 0);
        }
      }
    }
    cur ^= 1;
  }

  unsigned short* cp = ctx + (size_t)(wmin + lg * 4) * Dsz + h * HDn + l15;
#pragma unroll
  for (int nf = 0; nf < 8; nf++)
#pragma unroll
    for (int r = 0; r < 4; r++)
      cp[(size_t)r * Dsz + nf * 16] = f2bf(o[nf][r] / lrow[r]);
}

extern "C" void kernel_launch(void* const* d_in, const int* in_sizes, int n_in,
                              void* d_out, int out_size, void* d_ws, size_t ws_size,
                              hipStream_t stream) {
  (void)in_sizes; (void)n_in; (void)out_size; (void)ws_size;
  const float* x  = (const float*)d_in[0];
  // d_in[1] = mask: causality is hardcoded, never read
  const float* wq = (const float*)d_in[2];
  const float* wk = (const float*)d_in[3];
  const float* wv = (const float*)d_in[4];
  const float* wo = (const float*)d_in[5];
  const float* cs = (const float*)d_in[6];
  const float* sn = (const float*)d_in[7];
  float* out = (float*)d_out;

  unsigned short* ws16  = (unsigned short*)d_ws;
  unsigned short* WTqkv = ws16;                          // 3072*2048 (wq^T|wk^T|wv^T)
  unsigned short* WTo   = WTqkv + 3072 * 2048;           // 2048*2048
  unsigned short* xb    = WTo   + 2048 * 2048;           // 4096*2048
  unsigned short* Qb    = xb    + 4096 * 2048;           // 4096*2048 (rope'd, *1/sqrt(HD))
  unsigned short* Kb    = Qb    + 4096 * 2048;           // 4096*512  (rope'd)
  unsigned short* Vt    = Kb    + 4096 * 512;            // 512*4096  (V transposed)
  unsigned short* ctx   = Vt    + 512 * 4096;            // 4096*2048
  float* Cqkv = (float*)(ctx + 4096 * 2048);             // 4096*3072 f32

  k_cast_bf16<<<4096, 256, 0, stream>>>(x, xb, 4096 * 2048);
  k_transpose<<<dim3(32, 32), 256, 0, stream>>>(wq, 2048, WTqkv,              2048, 2048, 2048);
  k_transpose<<<dim3(8, 32),  256, 0, stream>>>(wk, 512,  WTqkv + 2048 * 2048, 2048, 2048, 512);
  k_transpose<<<dim3(8, 32),  256, 0, stream>>>(wv, 512,  WTqkv + 2560 * 2048, 2048, 2048, 512);
  k_transpose<<<dim3(32, 32), 256, 0, stream>>>(wo, 2048, WTo,                2048, 2048, 2048);

  // Cqkv = xb @ [wq|wk|wv]
  k_gemm_bt<<<dim3(24, 32), 256, 0, stream>>>(xb, WTqkv, Cqkv, 4096, 3072, 2048, 3072);
  k_rope<<<4096, 256, 0, stream>>>(Cqkv, cs, sn, Qb, Kb);
  // Vt = (Cqkv V-block)^T, cast bf16
  k_transpose<<<dim3(8, 64), 256, 0, stream>>>(Cqkv + 2560, 3072, Vt, 4096, 4096, 512);

  k_attn<<<dim3(512), 512, 0, stream>>>(Qb, Kb, Vt, ctx);

  // out = ctx @ wo
  k_gemm_bt<<<dim3(16, 32), 256, 0, stream>>>(ctx, WTo, out, 4096, 2048, 2048, 2048);
}

// Round 7
// 416.677 us; speedup vs baseline: 2.6198x; 1.1445x over previous
//
#include <hip/hip_runtime.h>
#include <cstdint>

#define Ssz 4096
#define Dsz 2048
#define Hn  16
#define Gn  4
#define HDn 128

typedef __attribute__((ext_vector_type(8))) short short8;
typedef __attribute__((ext_vector_type(8))) unsigned short u16x8;
typedef __attribute__((ext_vector_type(4))) float f32x4;

typedef __attribute__((address_space(1))) void gbl_void;
typedef __attribute__((address_space(3))) void lds_void;

static __device__ __forceinline__ unsigned short f2bf(float f) {
  uint32_t u = __builtin_bit_cast(uint32_t, f);
  u += 0x7FFFu + ((u >> 16) & 1u);   // RNE (no NaNs in this workload)
  return (unsigned short)(u >> 16);
}

// global -> LDS direct copy, 16B per lane. LDS dest is wave-uniform base
// (HW adds lane*16); global source address is per-lane.
static __device__ __forceinline__ void gload_lds16(const void* g, void* l) {
  __builtin_amdgcn_global_load_lds((gbl_void*)(uintptr_t)g,
                                   (lds_void*)(uintptr_t)l, 16, 0, 0);
}

// ---------------- cast f32 -> bf16, 8 elems/thread ----------------
__global__ void k_cast_bf16(const float* __restrict__ src,
                            unsigned short* __restrict__ dst, int n) {
  int base = (blockIdx.x * blockDim.x + threadIdx.x) * 8;
  if (base >= n) return;
  float4 a = *reinterpret_cast<const float4*>(src + base);
  float4 b = *reinterpret_cast<const float4*>(src + base + 4);
  u16x8 o;
  o[0] = f2bf(a.x); o[1] = f2bf(a.y); o[2] = f2bf(a.z); o[3] = f2bf(a.w);
  o[4] = f2bf(b.x); o[5] = f2bf(b.y); o[6] = f2bf(b.z); o[7] = f2bf(b.w);
  *reinterpret_cast<u16x8*>(dst + base) = o;
}

// ---------------- transpose f32 (R x C) -> bf16 (C x R), 64x64 tiles ----------------
__global__ void k_transpose(const float* __restrict__ src, int srcStride,
                            unsigned short* __restrict__ dst, int dstStride,
                            int R, int C) {
  __shared__ unsigned short tile[64][65];
  const int r0 = blockIdx.y * 64, c0 = blockIdx.x * 64;
  const int t  = threadIdx.x;
  const int rr = t >> 2;           // 0..63
  const int cc = (t & 3) * 16;     // 0,16,32,48
  const float* sp = src + (size_t)(r0 + rr) * srcStride + c0 + cc;
#pragma unroll
  for (int j = 0; j < 16; j += 4) {
    float4 v = *reinterpret_cast<const float4*>(sp + j);
    tile[rr][cc + j + 0] = f2bf(v.x);
    tile[rr][cc + j + 1] = f2bf(v.y);
    tile[rr][cc + j + 2] = f2bf(v.z);
    tile[rr][cc + j + 3] = f2bf(v.w);
  }
  __syncthreads();
  unsigned short* dp = dst + (size_t)(c0 + rr) * dstStride + r0 + cc;
  u16x8 o0, o1;
#pragma unroll
  for (int j = 0; j < 8; j++) o0[j] = tile[cc + j][rr];
#pragma unroll
  for (int j = 0; j < 8; j++) o1[j] = tile[cc + 8 + j][rr];
  *reinterpret_cast<u16x8*>(dp)     = o0;
  *reinterpret_cast<u16x8*>(dp + 8) = o1;
}

// ---------------- RoPE on Q (cols 0..2047) and K (cols 2048..2559) of Cqkv ----------------
__global__ void k_rope(const float* __restrict__ Cqkv,
                       const float* __restrict__ cosp, const float* __restrict__ sinp,
                       unsigned short* __restrict__ Qb, unsigned short* __restrict__ Kb) {
  const int s = blockIdx.x;
  const float* row = Cqkv + (size_t)s * 3072;
  const float qscale = 0.08838834764831845f;  // 1/sqrt(128)
  for (int c = threadIdx.x; c < 2560; c += 256) {
    int d = c & 127;
    float v = row[c];
    int pc = (d < 64) ? c + 64 : c - 64;
    float pv = row[pc];
    float rot = (d < 64) ? -pv : pv;
    float o = v * cosp[s * 128 + d] + rot * sinp[s * 128 + d];
    if (c < 2048)
      Qb[(size_t)s * 2048 + c] = f2bf(o * qscale);
    else
      Kb[(size_t)s * 512 + (c - 2048)] = f2bf(o);
  }
}

// ---------------- bf16 GEMM: C(f32, M x N, ldc) = A(M x K) * BT(N x K)^T ----------------
// m97 structure: 128x128 tile, BK=32, 4 waves (2x2), 4x4 16x16x32 frags per wave.
// XCD-aware blockIdx swizzle (grid must be a multiple of 8 blocks).
__global__ __launch_bounds__(256) void k_gemm_bt(
    const unsigned short* __restrict__ A, const unsigned short* __restrict__ BT,
    float* __restrict__ C, int M, int N, int K, int ldc) {
  __shared__ __align__(16) unsigned short sA[128 * 32];
  __shared__ __align__(16) unsigned short sB[128 * 32];
  const int tid = threadIdx.x;
  const int lane = tid & 63, wid = tid >> 6;
  const int bid = blockIdx.y * gridDim.x + blockIdx.x;
  const int cpx = (gridDim.x * gridDim.y) >> 3;
  const int swz = (bid & 7) * cpx + (bid >> 3);
  const int m0 = (swz / gridDim.x) * 128, n0 = (swz % gridDim.x) * 128;
  const int wm = (wid >> 1) * 64, wn = (wid & 1) * 64;
  const int l15 = lane & 15, lg = lane >> 4;
  const int srow = lane >> 2;         // row within 16-row staging chunk
  const int scol = (lane & 3) * 8;    // elem col within BK

  f32x4 acc[4][4] = {};

  for (int kt = 0; kt < K; kt += 32) {
#pragma unroll
    for (int c = 0; c < 2; c++) {
      const int row = c * 64 + wid * 16;
      gload_lds16(A  + (size_t)(m0 + row + srow) * K + kt + scol, sA + row * 32);
      gload_lds16(BT + (size_t)(n0 + row + srow) * K + kt + scol, sB + row * 32);
    }
    __syncthreads();
    short8 af[4], bf[4];
#pragma unroll
    for (int i = 0; i < 4; i++) {
      af[i] = *reinterpret_cast<const short8*>(sA + (wm + i * 16 + l15) * 32 + lg * 8);
      bf[i] = *reinterpret_cast<const short8*>(sB + (wn + i * 16 + l15) * 32 + lg * 8);
    }
#pragma unroll
    for (int i = 0; i < 4; i++)
#pragma unroll
      for (int j = 0; j < 4; j++)
        acc[i][j] = __builtin_amdgcn_mfma_f32_16x16x32_bf16(af[i], bf[j], acc[i][j], 0, 0, 0);
    __syncthreads();
  }

  const int rbase = m0 + wm + lg * 4;
  const int cbase = n0 + wn + l15;
#pragma unroll
  for (int i = 0; i < 4; i++)
#pragma unroll
    for (int j = 0; j < 4; j++)
#pragma unroll
      for (int r = 0; r < 4; r++)
        C[(size_t)(rbase + i * 16 + r) * ldc + cbase + j * 16] = acc[i][j][r];
}

// ---------------- causal GQA flash attention, v4 ----------------
// v3 + swapped QK^T: sc = mfma(K, Q) -> lane holds S[kv=f*16+lg*4+r][q=l15].
// Row softmax is in-lane (15 ops) + 2 shfl_xor; stats are per-lane scalars.
// P packed to bf16 pairs in-register, 4x ds_write_b64 (kv-contiguous rows),
// same XOR swizzle both sides, 2x ds_read_b128 back as PV A-frags.
__global__ __launch_bounds__(512, 4) void k_attn(
    const unsigned short* __restrict__ Qb, const unsigned short* __restrict__ Kb,
    const unsigned short* __restrict__ Vt, unsigned short* __restrict__ ctx) {
  __shared__ __align__(16) char sK[2][16384];   // [buf][64 kv][256B], swizzled
  __shared__ __align__(16) char sV[2][16384];   // [buf][128 d][128B], swizzled
  __shared__ __align__(16) char sP[8][2048];    // [wave][16 q][128B], swizzled
  const int id = blockIdx.x;                    // 0..511
  const int kid = id & 255;
  const int h = kid & 15, g = h >> 2;
  const int j = kid >> 4;                       // 0..15
  const int qt = (id < 256) ? (31 - j) : j;     // long blocks first
  const int qb = qt * 128;
  const int lane = threadIdx.x & 63, wid = threadIdx.x >> 6;
  const int l15 = lane & 15, lg = lane >> 4;
  const int sw = (l15 & 7) << 4;
  const int wmin = qb + wid * 16;
  const int nt = qt * 2 + 2;

  // per-lane pre-swizzled staging source offsets (bytes)
  const char* kbyte = (const char*)Kb;
  const char* vbyte = (const char*)Vt;
  int kOff[2], vOff[2];
#pragma unroll
  for (int q = 0; q < 2; q++) {
    int rk = wid * 8 + q * 4 + (lane >> 4);             // K tile row 0..63
    kOff[q] = rk * 1024 + g * 256 + (((lane & 15) * 16) ^ ((rk & 7) << 4));
    int rv = wid * 16 + q * 8 + (lane >> 3);            // V tile row (d) 0..127
    vOff[q] = (g * 128 + rv) * 8192 + (((lane & 7) * 16) ^ ((rv & 7) << 4));
  }

  auto stage = [&](int t, int b) {
    const char* ks = kbyte + (size_t)t * 65536;   // kv0*1024
    const char* vs = vbyte + (size_t)t * 128;     // kv0*2
#pragma unroll
    for (int q = 0; q < 2; q++)
      gload_lds16(ks + kOff[q], &sK[b][(wid * 2 + q) * 1024]);
#pragma unroll
    for (int q = 0; q < 2; q++)
      gload_lds16(vs + vOff[q], &sV[b][(wid * 2 + q) * 1024]);
  };

  // hoist Q fragments (L2-resident); B-operand layout: col=q=l15, k=lg*8+i
  short8 qf[4];
  {
    const unsigned short* qp = Qb + (size_t)(wmin + l15) * Dsz + h * HDn + lg * 8;
#pragma unroll
    for (int kk = 0; kk < 4; kk++)
      qf[kk] = *reinterpret_cast<const short8*>(qp + kk * 32);
  }

  f32x4 o[8] = {};
  float mrow_s = -1e30f, lrow_s = 0.f;   // stats for q-row l15

  stage(0, 0);
  int cur = 0;

  for (int t = 0; t < nt; t++) {
    asm volatile("s_waitcnt vmcnt(0)" ::: "memory");
    __syncthreads();                       // tile t staged & buf cur^1 free
    if (t + 1 < nt) stage(t + 1, cur ^ 1); // prefetch overlaps compute below
    const int kv0 = t * 64;
    if (kv0 <= wmin + 15) {
      // ---- QK^T (swapped: A=K, B=Q) -> sc[f][r] = S[kv0+f*16+lg*4+r][wmin+l15]
      f32x4 sc[4] = {};
#pragma unroll
      for (int f = 0; f < 4; f++) {
        const char* kr = &sK[cur][(f * 16 + l15) * 256];
#pragma unroll
        for (int kk = 0; kk < 4; kk++) {
          short8 kf = *reinterpret_cast<const short8*>(kr + ((kk * 64 + lg * 16) ^ sw));
          sc[f] = __builtin_amdgcn_mfma_f32_16x16x32_bf16(kf, qf[kk], sc[f], 0, 0, 0);
        }
      }
      // ---- causal mask (diagonal tiles only) ----
      if (kv0 + 63 > wmin) {
        const int qa = wmin + l15;
#pragma unroll
        for (int f = 0; f < 4; f++) {
          int kv = kv0 + f * 16 + lg * 4;
#pragma unroll
          for (int r = 0; r < 4; r++)
            if (kv + r > qa) sc[f][r] = -1e30f;
        }
      }
      // ---- online softmax: in-lane over 16 kv, then xor-16/32 across lg ----
      float mx = sc[0][0];
#pragma unroll
      for (int f = 0; f < 4; f++)
#pragma unroll
        for (int r = 0; r < 4; r++) mx = fmaxf(mx, sc[f][r]);
      mx = fmaxf(mx, __shfl_xor(mx, 16));
      mx = fmaxf(mx, __shfl_xor(mx, 32));
      // defer-rescale: only rescale when max grew by > 8
      if (__any(mx > mrow_s + 8.f)) {
        float mn = fmaxf(mrow_s, mx);
        float scl = __expf(mrow_s - mn);
        mrow_s = mn;
        lrow_s *= scl;
        float s4[4];
#pragma unroll
        for (int r = 0; r < 4; r++)
          s4[r] = __shfl(scl, (lane & 48) | (lg * 4 + r));
#pragma unroll
        for (int nf = 0; nf < 8; nf++)
#pragma unroll
          for (int r = 0; r < 4; r++) o[nf][r] *= s4[r];
      }
#pragma unroll
      for (int f = 0; f < 4; f++)
#pragma unroll
        for (int r = 0; r < 4; r++) sc[f][r] = __expf(sc[f][r] - mrow_s);
      float rs = 0.f;
#pragma unroll
      for (int f = 0; f < 4; f++)
        rs += (sc[f][0] + sc[f][1]) + (sc[f][2] + sc[f][3]);
      rs += __shfl_xor(rs, 16);
      rs += __shfl_xor(rs, 32);
      lrow_s += rs;

      // ---- P pack -> 4x ds_write_b64 (row q=l15, bytes = kv*2), swizzled ----
      char* plw = &sP[wid][0];
#pragma unroll
      for (int f = 0; f < 4; f++) {
        uint32_t w0 = (uint32_t)f2bf(sc[f][0]) | ((uint32_t)f2bf(sc[f][1]) << 16);
        uint32_t w1 = (uint32_t)f2bf(sc[f][2]) | ((uint32_t)f2bf(sc[f][3]) << 16);
        *reinterpret_cast<uint2*>(plw + l15 * 128 + ((f * 32 + lg * 8) ^ sw)) =
            make_uint2(w0, w1);
      }
      short8 pa[2];
#pragma unroll
      for (int kk = 0; kk < 2; kk++)
        pa[kk] = *reinterpret_cast<const short8*>(
            plw + l15 * 128 + ((kk * 64 + lg * 16) ^ sw));
      // ---- PV ----
#pragma unroll
      for (int nf = 0; nf < 8; nf++) {
        const char* vr = &sV[cur][(nf * 16 + l15) * 128];
#pragma unroll
        for (int kk = 0; kk < 2; kk++) {
          short8 vb = *reinterpret_cast<const short8*>(vr + ((kk * 64 + lg * 16) ^ sw));
          o[nf] = __builtin_amdgcn_mfma_f32_16x16x32_bf16(pa[kk], vb, o[nf], 0, 0, 0);
        }
      }
    }
    cur ^= 1;
  }

  // fetch l for q-rows lg*4+r (stats live in lanes with l15 == q)
  float lr4[4];
#pragma unroll
  for (int r = 0; r < 4; r++)
    lr4[r] = __shfl(lrow_s, (lane & 48) | (lg * 4 + r));
  unsigned short* cp = ctx + (size_t)(wmin + lg * 4) * Dsz + h * HDn + l15;
#pragma unroll
  for (int nf = 0; nf < 8; nf++)
#pragma unroll
    for (int r = 0; r < 4; r++)
      cp[(size_t)r * Dsz + nf * 16] = f2bf(o[nf][r] / lr4[r]);
}

extern "C" void kernel_launch(void* const* d_in, const int* in_sizes, int n_in,
                              void* d_out, int out_size, void* d_ws, size_t ws_size,
                              hipStream_t stream) {
  (void)in_sizes; (void)n_in; (void)out_size; (void)ws_size;
  const float* x  = (const float*)d_in[0];
  // d_in[1] = mask: causality is hardcoded, never read
  const float* wq = (const float*)d_in[2];
  const float* wk = (const float*)d_in[3];
  const float* wv = (const float*)d_in[4];
  const float* wo = (const float*)d_in[5];
  const float* cs = (const float*)d_in[6];
  const float* sn = (const float*)d_in[7];
  float* out = (float*)d_out;

  unsigned short* ws16  = (unsigned short*)d_ws;
  unsigned short* WTqkv = ws16;                          // 3072*2048 (wq^T|wk^T|wv^T)
  unsigned short* WTo   = WTqkv + 3072 * 2048;           // 2048*2048
  unsigned short* xb    = WTo   + 2048 * 2048;           // 4096*2048
  unsigned short* Qb    = xb    + 4096 * 2048;           // 4096*2048 (rope'd, *1/sqrt(HD))
  unsigned short* Kb    = Qb    + 4096 * 2048;           // 4096*512  (rope'd)
  unsigned short* Vt    = Kb    + 4096 * 512;            // 512*4096  (V transposed)
  unsigned short* ctx   = Vt    + 512 * 4096;            // 4096*2048
  float* Cqkv = (float*)(ctx + 4096 * 2048);             // 4096*3072 f32

  k_cast_bf16<<<4096, 256, 0, stream>>>(x, xb, 4096 * 2048);
  k_transpose<<<dim3(32, 32), 256, 0, stream>>>(wq, 2048, WTqkv,              2048, 2048, 2048);
  k_transpose<<<dim3(8, 32),  256, 0, stream>>>(wk, 512,  WTqkv + 2048 * 2048, 2048, 2048, 512);
  k_transpose<<<dim3(8, 32),  256, 0, stream>>>(wv, 512,  WTqkv + 2560 * 2048, 2048, 2048, 512);
  k_transpose<<<dim3(32, 32), 256, 0, stream>>>(wo, 2048, WTo,                2048, 2048, 2048);

  // Cqkv = xb @ [wq|wk|wv]
  k_gemm_bt<<<dim3(24, 32), 256, 0, stream>>>(xb, WTqkv, Cqkv, 4096, 3072, 2048, 3072);
  k_rope<<<4096, 256, 0, stream>>>(Cqkv, cs, sn, Qb, Kb);
  // Vt = (Cqkv V-block)^T, cast bf16
  k_transpose<<<dim3(8, 64), 256, 0, stream>>>(Cqkv + 2560, 3072, Vt, 4096, 4096, 512);

  k_attn<<<dim3(512), 512, 0, stream>>>(Qb, Kb, Vt, ctx);

  // out = ctx @ wo
  k_gemm_bt<<<dim3(16, 32), 256, 0, stream>>>(ctx, WTo, out, 4096, 2048, 2048, 2048);
}